// Round 9
// baseline (549.670 us; speedup 1.0000x reference)
//
#include <hip/hip_runtime.h>

#define LOG2E 1.4426950408889634f
#define LN2   0.6931471805599453f

// Base = r7 (verified 122.6 us, absmax 0): fwd/bwd split, linear domain
//   alpha_t = D_t M alpha_{t-1} (fwd),  beta_{t-1} = M^T (d_t beta_t) (bwd),
// state broadcast via LDS uniform-address reads, integer-exponent rescale,
// join Z = beta_m^T alpha_m at the midpoint.
//
// Round-9 change: r7's step = 575 cyc = ~300 VALU issue + ~275 stall (LDS
// round-trip). r8 proved in-register shuffle walks are WORSE (814 cyc). So
// keep the LDS broadcast but split each chain across 2 waves (4 waves/block):
// lane pair (2k,2k+1) owns state k; each lane does 32 FMAs over its j-half
// (issue halved), pair-combine is ONE quad_perm DPP + add (no LDS round trip
// for the combine), each wave writes 32 complete states. Cross-wave
// visibility = one __syncthreads per step on a double-buffered state
// (write buf s&1, read buf (s-1)&1 -> single barrier, no WAR race).
// Reads are 8x ds_read_b128 with 2 distinct addresses per instr (per-lane
// j-half) = free 2-way broadcast. Anchor = extra uniform b32 read of p[0]
// (consistent across both waves of a chain -> identical base2 bookkeeping).
__device__ __forceinline__ float dpp_xor1(float v) {
  // quad_perm [1,0,3,2] (xor-1, self-inverse)
  return __int_as_float(
      __builtin_amdgcn_mov_dpp(__float_as_int(v), 0xB1, 0xf, 0xf, true));
}

__global__ __launch_bounds__(256, 2)
void crf_fwd_33852932227637(
    const float* __restrict__ h,
    const float* __restrict__ trans,
    const int* __restrict__ lengths,
    float* __restrict__ out,
    int T) {
  constexpr int N = 64;
  const int b = blockIdx.x;
  const int lane = threadIdx.x & 63;
  const int wv = threadIdx.x >> 6;  // 0..3
  const int chain = wv >> 1;        // 0 = fwd, 1 = bwd
  const int sblk = wv & 1;          // which 32-state block this wave owns
  const int i = sblk * 32 + (lane >> 1);  // owned state
  const int jh = lane & 1;                // j-half this lane reduces

  const float* hb = h + (size_t)b * T * N;
  const int len = lengths[b];
  const int m = (len - 1) >> 1;     // join point
  const int nsF = m;                // fwd matvecs: t = 1..m
  const int nsB = len - 1 - m;      // bwd matvecs: t = len-1..m+1
  const int S = nsB;                // nsB >= nsF always
  const int ns = chain ? nsB : nsF; // this wave's active step count

  // M fragment: 32 values = M[i][32jh .. 32jh+31] (fwd) or the same row of
  // M^T (bwd: trans[j][i]). Prologue-only, L2-resident.
  float Mreg[32];
  if (chain == 0) {
    const float4* tr4 = (const float4*)(trans + i * N + 32 * jh);
#pragma unroll
    for (int q = 0; q < 8; ++q) {
      float4 tq = tr4[q];
      Mreg[4 * q + 0] = __builtin_amdgcn_exp2f(tq.x * LOG2E);
      Mreg[4 * q + 1] = __builtin_amdgcn_exp2f(tq.y * LOG2E);
      Mreg[4 * q + 2] = __builtin_amdgcn_exp2f(tq.z * LOG2E);
      Mreg[4 * q + 3] = __builtin_amdgcn_exp2f(tq.w * LOG2E);
    }
  } else {
#pragma unroll
    for (int k = 0; k < 32; ++k)
      Mreg[k] = __builtin_amdgcn_exp2f(trans[(32 * jh + k) * N + i] * LOG2E);
  }
  // Pin into arch VGPRs (r2: backend otherwise parks arrays in AGPR/scratch).
#pragma unroll
  for (int q = 0; q < 4; ++q) {
    asm volatile("" : "+v"(Mreg[8 * q + 0]), "+v"(Mreg[8 * q + 1]),
                      "+v"(Mreg[8 * q + 2]), "+v"(Mreg[8 * q + 3]),
                      "+v"(Mreg[8 * q + 4]), "+v"(Mreg[8 * q + 5]),
                      "+v"(Mreg[8 * q + 6]), "+v"(Mreg[8 * q + 7]));
  }

  // Double-buffered state per chain. 1 KiB total.
  __shared__ __align__(16) float pf[2][2][N];
  __shared__ int xb2s;

  // Init state (both lanes of a pair compute the identical value and write
  // the same address with it — LDS resolves same-addr same-value benignly).
  // FWD: alpha_0[i] = exp(h[0,i]+trans[i,START]); BWD: u_END (fold d_{len-1}
  // when there is at least one matvec). START=N-2, END=N-1.
  float v;
  if (chain == 0) {
    v = __builtin_amdgcn_exp2f((hb[i] + trans[i * N + (N - 2)]) * LOG2E);
  } else {
    v = __builtin_amdgcn_exp2f(trans[(N - 1) * N + i] * LOG2E);
    if (nsB >= 1)
      v *= __builtin_amdgcn_exp2f(hb[(size_t)(len - 1) * N + i] * LOG2E);
  }
  pf[chain][0][i] = v;
  int base2 = 0;
  __syncthreads();

  // Emission time for logical step s of this chain (clamped address; value
  // unused when clamped). FWD step s consumes d_s; BWD folded step s
  // consumes d_{len-1-s}; BWD raw step (s == nsB) uses D = 1.
  auto emit_t = [&](int s_) -> int {
    int t = chain == 0 ? s_ : (len - 1 - s_);
    if (t < 0) t = 0;
    if (t > T - 1) t = T - 1;
    return t;
  };
  float eb[4];
#pragma unroll
  for (int u = 0; u < 4; ++u)
    eb[u] = __builtin_amdgcn_exp2f(hb[(size_t)emit_t(1 + u) * N + i] * LOG2E);

  for (int s = 1; s <= S; ++s) {
    const int rb = (s - 1) & 1, wb = s & 1;
    const float4* p4 = (const float4*)&pf[chain][rb][32 * jh];
    float anch = pf[chain][rb][0];  // uniform b32 read: shared anchor
    float a0 = 0.f, a1 = 0.f, a2 = 0.f, a3 = 0.f;
#pragma unroll
    for (int g = 0; g < 8; ++g) {
      float4 q = p4[g];  // 2 distinct addrs/instr -> free 2-way broadcast
      a0 = fmaf(Mreg[4 * g + 0], q.x, a0);
      a1 = fmaf(Mreg[4 * g + 1], q.y, a1);
      a2 = fmaf(Mreg[4 * g + 2], q.z, a2);
      a3 = fmaf(Mreg[4 * g + 3], q.w, a3);
    }
    float part = (a0 + a1) + (a2 + a3);
    float sum = part + dpp_xor1(part);  // pair combine: full dot for state i

    // Scale bookkeeping off the chain-critical ops: anchor exponent ->
    // mult; applied only while this chain is active.
    int e = (int)((__float_as_uint(anch) >> 23) & 0xffu);
    float D = 1.0f;
    if (chain == 0) {
      D = eb[(s - 1) & 3];
    } else if (s <= nsB - 1) {
      D = eb[(s - 1) & 3];
    }  // s == nsB: raw final bwd step, D = 1
    float mult = D * __uint_as_float((unsigned)(254 - e) << 23);  // 2^(127-e)
    bool active = s <= ns;  // wave-uniform
    if (active) {
      v = sum * mult;
      base2 += e - 127;
    }
    pf[chain][wb][i] = v;  // active: new state; inactive: copy-forward
    __syncthreads();

    eb[(s - 1) & 3] =
        __builtin_amdgcn_exp2f(hb[(size_t)emit_t(s + 4) * N + i] * LOG2E);
  }

  // Join: Z * 2^-(b2F+b2B) = sum_i alpha_m[i] * beta_m[i].
  if (wv == 2 && lane == 0) xb2s = base2;  // bwd chain's base2
  __syncthreads();
  if (wv == 0) {
    const int fb = S & 1;
    float z = pf[0][fb][lane] * pf[1][fb][lane];
#pragma unroll
    for (int off = 32; off >= 1; off >>= 1)
      z += __shfl_xor(z, off, 64);
    if (lane == 0)
      out[b] = LN2 * ((float)(base2 + xb2s) + __builtin_amdgcn_logf(z));
  }
}

extern "C" void kernel_launch(void* const* d_in, const int* in_sizes, int n_in,
                              void* d_out, int out_size, void* d_ws, size_t ws_size,
                              hipStream_t stream) {
  const float* h = (const float*)d_in[0];
  const float* trans = (const float*)d_in[1];
  const int* lengths = (const int*)d_in[2];
  float* out = (float*)d_out;
  const int B = in_sizes[2];
  const int N = 64;
  const int T = in_sizes[0] / (B * N);
  crf_fwd_33852932227637<<<B, N * 4, 0, stream>>>(h, trans, lengths, out, T);
}

// Round 11
// 240.488 us; speedup vs baseline: 2.2856x; 2.2856x over previous
//
#include <hip/hip_runtime.h>

#define LOG2E 1.4426950408889634f
#define LN2   0.6931471805599453f

typedef float f32x2 __attribute__((ext_vector_type(2)));

// Base = r7 (verified 122.6 us, absmax 0): fwd/bwd split, linear domain
//   alpha_t = D_t M alpha_{t-1} (fwd),  beta_{t-1} = M^T (d_t beta_t) (bwd),
// one wave per chain, state broadcast via LDS uniform-address ds_read_b128,
// IMMEDIATE integer-exponent rescale every 2 steps (r7's scheme — r10's
// deferred old-state anchor had a 2-step-lag feedback whose period-6
// resonance is marginally unstable and overflowed; rescale lag must be <=1),
// join Z = beta_m^T alpha_m at the midpoint.
//
// Round-11 change (the ONLY change vs r7): packed math. The ds_read_b128
// payload is two aligned f32 pairs; M is pre-packed as f32x2; 64 v_fma ->
// 32 v_pk_fma_f32 + packed add tree. VGPR x VGPR operands only, emitted via
// __builtin_elementwise_fma — no inline-asm scheduling (r3), no SGPR-pair
// operands (r3), no cross-wave sync (r1/r9), no deferred rescale (r10).
template <bool FWD>
__device__ __forceinline__ void run_chain(
    const float* __restrict__ hb, const float* __restrict__ trans,
    float* __restrict__ pbuf, int lane, int len, int nsteps, int& b2Out) {
  constexpr int N = 64;

  // M fragment as 32 packed pairs: FWD lane i holds row i of M=exp(trans);
  // BWD lane j holds column j (row j of M^T). Prologue-only, L2-resident.
  f32x2 Mp[N / 2];
  if (FWD) {
    const float4* trow = (const float4*)(trans + lane * N);
#pragma unroll
    for (int q = 0; q < 16; ++q) {
      float4 tq = trow[q];
      Mp[2 * q + 0] = {__builtin_amdgcn_exp2f(tq.x * LOG2E),
                       __builtin_amdgcn_exp2f(tq.y * LOG2E)};
      Mp[2 * q + 1] = {__builtin_amdgcn_exp2f(tq.z * LOG2E),
                       __builtin_amdgcn_exp2f(tq.w * LOG2E)};
    }
  } else {
#pragma unroll
    for (int q = 0; q < 32; ++q) {
      Mp[q] = {__builtin_amdgcn_exp2f(trans[(2 * q + 0) * N + lane] * LOG2E),
               __builtin_amdgcn_exp2f(trans[(2 * q + 1) * N + lane] * LOG2E)};
    }
  }
  // Pin into arch VGPR pairs (r2/r9: backend otherwise parks arrays in
  // AGPRs or scratch; VGPR_Count in counters is the tripwire).
#pragma unroll
  for (int q = 0; q < 8; ++q) {
    asm volatile("" : "+v"(Mp[4 * q + 0]), "+v"(Mp[4 * q + 1]),
                      "+v"(Mp[4 * q + 2]), "+v"(Mp[4 * q + 3]));
  }

  // Init state in LDS. FWD: alpha_0[i] = exp(h[0,i]+trans[i,START]).
  // BWD: u_END[i] = exp(trans[END,i]), folding d_{len-1} when there is at
  // least one matvec (write-folded scheme). START=N-2, END=N-1.
  {
    float v;
    if (FWD) {
      v = __builtin_amdgcn_exp2f((hb[lane] + trans[lane * N + (N - 2)]) * LOG2E);
    } else {
      v = __builtin_amdgcn_exp2f(trans[(N - 1) * N + lane] * LOG2E);
      if (nsteps >= 1)
        v *= __builtin_amdgcn_exp2f(hb[(size_t)(len - 1) * N + lane] * LOG2E);
    }
    pbuf[lane] = v;
  }
  int base2 = 0;

  // Folded-step count: FWD runs all nsteps with D applied after the matvec;
  // BWD runs nsteps-1 with D folded at write, then one final RAW step
  // (beta_m must exclude d_m).
  const int ns = FWD ? nsteps : nsteps - 1;

  auto step = [&](float D, bool resc) {
    const float4* pb4 = (const float4*)pbuf;
    f32x2 a0 = {0.f, 0.f}, a1 = {0.f, 0.f}, a2 = {0.f, 0.f}, a3 = {0.f, 0.f};
    float p0ref = 0.f;
#pragma unroll
    for (int g = 0; g < 16; ++g) {
      float4 q = pb4[g];  // uniform address -> ds_read_b128 broadcast
      if (g == 0) p0ref = q.x;
      f32x2 qlo = {q.x, q.y}, qhi = {q.z, q.w};
      if ((g & 1) == 0) {
        a0 = __builtin_elementwise_fma(Mp[2 * g + 0], qlo, a0);
        a1 = __builtin_elementwise_fma(Mp[2 * g + 1], qhi, a1);
      } else {
        a2 = __builtin_elementwise_fma(Mp[2 * g + 0], qlo, a2);
        a3 = __builtin_elementwise_fma(Mp[2 * g + 1], qhi, a3);
      }
    }
    float mult = D;
    if (resc) {  // anchor = replicated p[0] of the state being consumed
      unsigned bits = __float_as_uint(p0ref);
      int e = (int)((bits >> 23) & 0xffu);
      base2 += e - 127;
      mult *= __uint_as_float((unsigned)(254 - e) << 23);  // 2^(127-e)
    }
    f32x2 s01 = a0 + a1, s23 = a2 + a3;  // v_pk_add_f32
    f32x2 s2 = s01 + s23;
    pbuf[lane] = (s2.x + s2.y) * mult;  // per-lane write, 2-way alias = free
  };

  // Emission for folded step s: FWD t = s; BWD t = len-1-s (write-fold).
  auto emit_of = [&](int s_) -> float {
    int smax = ns < 1 ? 1 : ns;
    int sc = s_ < smax ? s_ : smax;
    if (sc < 1) sc = 1;
    int t = FWD ? sc : (len - 1 - sc);
    if (t < 0) t = 0;  // value unused in these cases; keep address in range
    return __builtin_amdgcn_exp2f(hb[(size_t)t * N + lane] * LOG2E);
  };

  float eb[8];
#pragma unroll
  for (int u = 0; u < 8; ++u) eb[u] = emit_of(1 + u);

  int s = 1;
  for (; s + 8 <= ns + 1; s += 8) {
#pragma unroll
    for (int u = 0; u < 8; ++u) {
      step(eb[u], (u & 1) == 1);  // rescale every 2 steps
      eb[u] = emit_of(s + u + 8);
    }
  }
  for (; s <= ns; ++s) {  // tail; slot for step s is (s-1)&7
    step(eb[(s - 1) & 7], true);
  }
  if (!FWD && nsteps >= 1) step(1.0f, true);  // final raw beta_m step

  b2Out = base2;
}

__global__ __launch_bounds__(128)
__attribute__((amdgpu_waves_per_eu(1, 1)))
void crf_fwd_33852932227637(
    const float* __restrict__ h,
    const float* __restrict__ trans,
    const int* __restrict__ lengths,
    float* __restrict__ out,
    int T) {
  constexpr int N = 64;
  const int b = blockIdx.x;
  const int lane = threadIdx.x & 63;
  const int wv = threadIdx.x >> 6;

  const float* hb = h + (size_t)b * T * N;
  const int len = lengths[b];
  const int m = (len - 1) >> 1;  // fwd matvecs: 1..m ; bwd matvecs: len-1..m+1

  __shared__ __align__(16) float pbuf[2][N];
  __shared__ int xb2[2];

  int b2;
  if (wv == 0)
    run_chain<true>(hb, trans, pbuf[0], lane, len, m, b2);
  else
    run_chain<false>(hb, trans, pbuf[1], lane, len, len - 1 - m, b2);
  if (lane == 0) xb2[wv] = b2;
  __syncthreads();

  if (wv == 0) {
    // Z * 2^-(b2f+b2b) = sum_i alpha_m[i] * beta_m[i]; anchors keep both
    // factors ~2^0, so the dot neither over- nor underflows.
    float z = pbuf[0][lane] * pbuf[1][lane];
#pragma unroll
    for (int off = 32; off >= 1; off >>= 1)
      z += __shfl_xor(z, off, 64);
    if (lane == 0)
      out[b] = LN2 * ((float)(xb2[0] + xb2[1]) + __builtin_amdgcn_logf(z));
  }
}

extern "C" void kernel_launch(void* const* d_in, const int* in_sizes, int n_in,
                              void* d_out, int out_size, void* d_ws, size_t ws_size,
                              hipStream_t stream) {
  const float* h = (const float*)d_in[0];
  const float* trans = (const float*)d_in[1];
  const int* lengths = (const int*)d_in[2];
  float* out = (float*)d_out;
  const int B = in_sizes[2];
  const int N = 64;
  const int T = in_sizes[0] / (B * N);
  crf_fwd_33852932227637<<<B, N * 2, 0, stream>>>(h, trans, lengths, out, T);
}